// Round 3
// baseline (81.633 us; speedup 1.0000x reference)
//
#include <hip/hip_runtime.h>
#include <math.h>

#define NQ   16
#define NTH  512
#define NB   512

typedef float2 c32;

__device__ __forceinline__ c32 cmul(c32 a, c32 b) {
    return make_float2(a.x*b.x - a.y*b.y, a.x*b.y + a.y*b.x);
}
__device__ __forceinline__ c32 cfma_(c32 a, c32 b, c32 acc) {
    // acc += a*b
    acc.x = fmaf(a.x, b.x, fmaf(-a.y, b.y, acc.x));
    acc.y = fmaf(a.x, b.y, fmaf( a.y, b.x, acc.y));
    return acc;
}
__device__ __forceinline__ c32 cfmaConjA(c32 a, c32 b, c32 acc) {
    // acc += conj(a)*b
    acc.x = fmaf(a.x, b.x, fmaf( a.y, b.y, acc.x));
    acc.y = fmaf(a.x, b.y, fmaf(-a.y, b.x, acc.y));
    return acc;
}
__device__ __forceinline__ c32 cmulConjA(c32 a, c32 b) {
    return cfmaConjA(a, b, make_float2(0.f, 0.f));
}
__device__ __forceinline__ c32 cadd(c32 a, c32 b){ return make_float2(a.x+b.x, a.y+b.y); }

// Compact MPS (right-bond top bit == physical index):
//   interior q=1..14:  Ac[a, i, r] = U3[i^k3,m2]*U2[m2^k2,m1]*U1[m1^k1,m0]*w[k0,m0]
//   site 0: A0c[i,r]; site 15: A15[a,i] (dense). All L/R envs live on two
//   diagonal 8x8 blocks. 512 thr/block (1 batch elem), 2 blocks/CU -> 4 waves/SIMD.

__global__ __launch_bounds__(NTH, 4)
void pqc_mps_kernel(const float* __restrict__ ctx,
                    const float* __restrict__ Wm,
                    const float* __restrict__ bias,
                    const float* __restrict__ params,
                    float* __restrict__ out)
{
    __shared__ c32 Ac[14][272];     // sites 1..14; layout a*17 + i*8 + r
    __shared__ c32 A0c[16];         // i*8 + r
    __shared__ c32 A15v[32];        // a*2 + i
    __shared__ c32 Renv[15][144];   // R_q diag blocks: i*72 + bl*9 + bp
    __shared__ c32 Ssto[15][144];   // S at site q, same layout
    __shared__ c32 TR[272];         // R scratch: b*17 + i*8 + g'
    __shared__ c32 TL[272];         // L scratch: a*17 + i*8 + b'
    __shared__ c32 Lbuf[144];       // running L env
    __shared__ c32 Ug[256];         // fused RZ*RY*RX per (l,q)
    __shared__ c32 wv[64];          // w[q,k,i]
    __shared__ float angles[NQ];

    const int b = blockIdx.x;
    const int t = threadIdx.x;

    // ---- phase A: encoding angles -------------------------------------------
    {
        const int q = t >> 5, g = t & 31;
        const float* crow = ctx + b * 256;
        const float* wrow = Wm + q * 256;
        float s = 0.f;
        #pragma unroll
        for (int j = 0; j < 8; ++j)
            s += crow[g + 32*j] * wrow[g + 32*j];
        #pragma unroll
        for (int m = 16; m; m >>= 1) s += __shfl_xor(s, m);
        if (g == 0) angles[q] = 3.14159265358979323846f * tanhf(s + bias[q]);
    }
    if (t < 64) {  // U = RZ*RY*RX per (l,q)
        const float a  = params[t*3 + 0];
        const float bb = params[t*3 + 1];
        const float c  = params[t*3 + 2];
        const float ha = 0.5f*a, hb = 0.5f*bb, hc = 0.5f*c;
        const float ca = cosf(ha), sa = sinf(ha);
        const float cb = cosf(hb), sb = sinf(hb);
        const float cz = cosf(hc), sz = sinf(hc);
        const c32 m00 = make_float2( cb*ca,  sb*sa);
        const c32 m01 = make_float2(-sb*ca, -cb*sa);
        const c32 m10 = make_float2( sb*ca, -cb*sa);
        const c32 m11 = make_float2( cb*ca, -sb*sa);
        const c32 e0 = make_float2(cz, -sz);
        const c32 e1 = make_float2(cz,  sz);
        Ug[t*4 + 0] = cmul(e0, m00);
        Ug[t*4 + 1] = cmul(e0, m01);
        Ug[t*4 + 2] = cmul(e1, m10);
        Ug[t*4 + 3] = cmul(e1, m11);
    }
    __syncthreads();

    // ---- phase B: w[q,k,i] --------------------------------------------------
    if (t < 64) {
        const int q = t >> 2, k = (t>>1)&1, i = t&1;
        const float h = 0.5f * angles[q];
        const float ch = cosf(h), sh = sinf(h);
        const int r0 = (i ^ k) << 1;
        const c32 u0 = Ug[(q<<2) + r0];
        const c32 u1 = Ug[(q<<2) + r0 + 1];
        wv[t] = make_float2(u0.x*ch + u1.y*sh, u0.y*ch - u1.x*sh);
    }
    __syncthreads();

    // ---- phase C: build compact MPS tensors ---------------------------------
    {
        const int r = t & 7, i = (t>>3)&1, a = (t>>4)&15, h = t>>8;
        const int m0 = r&1, m1 = (r>>1)&1, m2 = r>>2;
        const int k0 = a&1, k1 = (a>>1)&1, k2 = (a>>2)&1, k3 = a>>3;
        #pragma unroll
        for (int qq = 0; qq < 7; ++qq) {
            const int q = 1 + h*7 + qq;
            const c32 u3 = Ug[((48+q)<<2) + ((i ^k3)<<1) + m2];
            const c32 u2 = Ug[((32+q)<<2) + ((m2^k2)<<1) + m1];
            const c32 u1 = Ug[((16+q)<<2) + ((m1^k1)<<1) + m0];
            const c32 ww = wv[(q<<2) + (k0<<1) + m0];
            Ac[q-1][a*17 + i*8 + r] = cmul(cmul(u3, u2), cmul(u1, ww));
        }
        if (t < 16) {  // site 0
            const c32 u3 = Ug[(48<<2) + (i <<1) + m2];
            const c32 u2 = Ug[(32<<2) + (m2<<1) + m1];
            const c32 u1 = Ug[(16<<2) + (m1<<1) + m0];
            A0c[t] = cmul(cmul(u3, u2), cmul(u1, wv[m0]));
        }
        if (t >= 64 && t < 96) {  // site 15 dense
            const int idx = t - 64, aa = idx >> 1, ii = idx & 1;
            const int K0 = aa&1, K1 = (aa>>1)&1, K2 = (aa>>2)&1, K3 = aa>>3;
            c32 y1[2], y2[2];
            #pragma unroll
            for (int j1 = 0; j1 < 2; ++j1) {
                const int rr = (j1 ^ K1) << 1;
                y1[j1] = cfma_(Ug[((16+15)<<2)+rr], wv[60 + (K0<<1)],
                         cmul (Ug[((16+15)<<2)+rr+1], wv[60 + (K0<<1) + 1]));
            }
            #pragma unroll
            for (int j2 = 0; j2 < 2; ++j2) {
                const int rr = (j2 ^ K2) << 1;
                y2[j2] = cfma_(Ug[((32+15)<<2)+rr], y1[0],
                         cmul (Ug[((32+15)<<2)+rr+1], y1[1]));
            }
            const int rr = (ii ^ K3) << 1;
            A15v[(aa<<1)+ii] = cfma_(Ug[((48+15)<<2)+rr], y2[0],
                               cmul (Ug[((48+15)<<2)+rr+1], y2[1]));
        }
    }
    __syncthreads();

    // ---- step 0: R_14 init and S[0]/L init ----------------------------------
    if (t < 128) {
        const int m = t>>6, bl = (t>>3)&7, bp = t&7;
        c32 acc = cmulConjA(A15v[((m<<3)+bl)<<1],       A15v[((m<<3)+bp)<<1]);
        acc     = cfmaConjA(A15v[(((m<<3)+bl)<<1) + 1], A15v[(((m<<3)+bp)<<1) + 1], acc);
        Renv[14][m*72 + bl*9 + bp] = acc;
    } else if (t < 256) {
        const int u = t-128, i = u>>6, bl = (u>>3)&7, bp = u&7;
        const c32 s = cmulConjA(A0c[(i<<3)+bl], A0c[(i<<3)+bp]);
        Ssto[0][i*72 + bl*9 + bp] = s;
        Lbuf   [i*72 + bl*9 + bp] = s;
    }
    __syncthreads();

    // ---- merged sweep -------------------------------------------------------
    for (int s = 1; s <= 14; ++s) {
        const c32* Ap = Ac[14 - s];      // site 15-s
        const c32* Rn = Renv[15 - s];
        const c32* As = Ac[s - 1];       // site s

        // phase 1: 512 single K=8 chains (256 TR + 256 TL)
        if (t < 256) {
            const int bb = t>>4, i = (t>>3)&1, gp = t&7;
            c32 tr = make_float2(0.f,0.f);
            #pragma unroll
            for (int g = 0; g < 8; ++g)
                tr = cfmaConjA(Ap[bb*17 + i*8 + g], Rn[i*72 + g*9 + gp], tr);
            TR[bb*17 + i*8 + gp] = tr;
        } else {
            const int u = t-256;
            const int bb = u>>4, i = (u>>3)&1, gp = u&7;
            const int m = bb>>3, al = bb&7;
            c32 tl = make_float2(0.f,0.f);
            #pragma unroll
            for (int g = 0; g < 8; ++g)
                tl = cfma_(Lbuf[m*72 + al*9 + g], As[(m*8+g)*17 + i*8 + gp], tl);
            TL[bb*17 + i*8 + gp] = tl;
        }
        __syncthreads();

        // phase 2: 512 K=8 partials, pair-combined via intra-wave shfl_xor(1)
        if (t < 256) {   // R: split K by i (lane bit 0)
            const int i = t&1, bp = (t>>1)&7, bl = (t>>4)&7, m = (t>>7)&1;
            const c32* trow = &TR[(m*8+bl)*17 + i*8];
            const c32* arow = &Ap[(m*8+bp)*17 + i*8];
            c32 r = make_float2(0.f,0.f);
            #pragma unroll
            for (int gp = 0; gp < 8; ++gp)
                r = cfma_(trow[gp], arow[gp], r);
            r.x += __shfl_xor(r.x, 1);
            r.y += __shfl_xor(r.y, 1);
            if (i == 0) Renv[14-s][m*72 + bl*9 + bp] = r;
        } else {         // S: split K by a-parity (lane bit 0)
            const int u = t-256;
            const int p = u&1, bp = (u>>1)&7, bl = (u>>4)&7, i = (u>>7)&1;
            c32 sv = make_float2(0.f,0.f);
            #pragma unroll
            for (int a2 = 0; a2 < 8; ++a2) {
                const int a = 2*a2 + p;
                sv = cfmaConjA(As[a*17 + i*8 + bl], TL[a*17 + i*8 + bp], sv);
            }
            sv.x += __shfl_xor(sv.x, 1);
            sv.y += __shfl_xor(sv.y, 1);
            if (p == 0) {
                Ssto[s][i*72 + bl*9 + bp] = sv;
                Lbuf   [i*72 + bl*9 + bp] = sv;
            }
        }
        __syncthreads();
    }

    // ---- Z phase ------------------------------------------------------------
    if (t < 256) {
        const int q = t >> 4, g = t & 15;
        float val = 0.f;
        if (q < 15) {
            const int i = g>>3, bl = g&7;
            const float sign = i ? -1.f : 1.f;
            const c32* Sq = &Ssto[q][i*72 + bl*9];
            const c32* Rq = &Renv[q][i*72 + bl*9];
            #pragma unroll
            for (int j = 0; j < 8; ++j)
                val += sign * (Sq[j].x*Rq[j].x - Sq[j].y*Rq[j].y);
        } else {
            const int m = g>>3, al = g&7;
            const c32 a0 = A15v[((m*8+al)<<1) + 0];
            const c32 a1 = A15v[((m*8+al)<<1) + 1];
            #pragma unroll
            for (int j = 0; j < 8; ++j) {
                c32 d = cmulConjA(a0, A15v[((m*8+j)<<1) + 0]);
                const c32 d1 = cmulConjA(a1, A15v[((m*8+j)<<1) + 1]);
                d.x -= d1.x; d.y -= d1.y;
                const c32 Lv = Lbuf[m*72 + al*9 + j];
                val += Lv.x*d.x - Lv.y*d.y;
            }
        }
        #pragma unroll
        for (int mm = 8; mm; mm >>= 1) val += __shfl_xor(val, mm);
        if (g == 0) out[b*NQ + q] = val;
    }
}

extern "C" void kernel_launch(void* const* d_in, const int* in_sizes, int n_in,
                              void* d_out, int out_size, void* d_ws, size_t ws_size,
                              hipStream_t stream) {
    const float* ctx    = (const float*)d_in[0];   // [512,256]
    const float* Wm     = (const float*)d_in[1];   // [16,256]
    const float* bias   = (const float*)d_in[2];   // [16]
    const float* params = (const float*)d_in[3];   // [4,16,3]
    float* out = (float*)d_out;                    // [512,16]
    (void)in_sizes; (void)n_in; (void)out_size; (void)d_ws; (void)ws_size;
    pqc_mps_kernel<<<NB, NTH, 0, stream>>>(ctx, Wm, bias, params, out);
}